// Round 8
// baseline (2163.650 us; speedup 1.0000x reference)
//
#include <hip/hip_runtime.h>

#define EPSF 1e-6f
#define ONEM 0.999999f
#define Bb 256
#define Tt 128
#define Kd 1024

typedef __attribute__((ext_vector_type(8))) short s16x8;
typedef __attribute__((ext_vector_type(4))) short s16x4;
typedef __attribute__((ext_vector_type(4))) float f32x4;
typedef unsigned long long ull;

union PF { ull u; float f[2]; };

__device__ __forceinline__ short f2bf(float f) {
  unsigned u = __float_as_uint(f);
  u += 0x7fffu + ((u >> 16) & 1u);
  return (short)(u >> 16);
}
__device__ __forceinline__ float bf2f(short s) {
  return __uint_as_float(((unsigned)(unsigned short)s) << 16);
}
// fast tanh/atanh via hw exp/log; abs err ~1e-7 (budget 1.85e-3)
__device__ __forceinline__ float ftanh(float x) {
  float e = __expf(2.f * x);
  return 1.f - 2.f / (e + 1.f);
}
__device__ __forceinline__ float fatanh(float x) {
  return 0.5f * __logf((1.f + x) / (1.f - x));
}
// sum over the 16 lanes of one lm-group
__device__ __forceinline__ float red16(float v) {
#pragma unroll
  for (int m = 8; m >= 1; m >>= 1) v += __shfl_xor(v, m, 64);
  return v;
}

// block-wide sum over 256 threads (setup kernels only)
__device__ __forceinline__ float brsum(float v) {
  __shared__ float sb[4];
#pragma unroll
  for (int m = 32; m >= 1; m >>= 1) v += __shfl_xor(v, m, 64);
  __syncthreads();
  if ((threadIdx.x & 63) == 0) sb[threadIdx.x >> 6] = v;
  __syncthreads();
  return sb[0] + sb[1] + sb[2] + sb[3];
}

// 16-arrival barrier, ALL RELAXED (no wbl2/inv cache ops). Ordering comes
// from __syncthreads' vmcnt(0) drain: my data-atomics are LLC-complete
// before my flag add issues; consumers read data with bypassing atomics.
__device__ __forceinline__ void gbarR(int* c) {
  __syncthreads();
  if (threadIdx.x == 0) {
    __hip_atomic_fetch_add(c, 1, __ATOMIC_RELAXED, __HIP_MEMORY_SCOPE_AGENT);
    while (__hip_atomic_load(c, __ATOMIC_RELAXED, __HIP_MEMORY_SCOPE_AGENT) < 16)
      __builtin_amdgcn_s_sleep(1);
  }
  __syncthreads();
}

// ---- transpose+convert W_ih (f32 [k][n]) -> WT bf16 [n][k] (for gemm_p)
__global__ void wcvt_kernel(const float* __restrict__ W, short* __restrict__ WT) {
  __shared__ float tile[64][65];
  const int k0 = blockIdx.y * 64, n0 = blockIdx.x * 64;
  const int t = threadIdx.x;
#pragma unroll
  for (int i = 0; i < 16; i++) {
    int e = i * 256 + t, r = e >> 6, c = e & 63;
    tile[r][c] = W[(k0 + r) * Kd + n0 + c];
  }
  __syncthreads();
#pragma unroll
  for (int i = 0; i < 16; i++) {
    int e = i * 256 + t, rn = e >> 6, ck = e & 63;
    WT[(n0 + rn) * Kd + k0 + ck] = f2bf(tile[ck][rn]);
  }
}

// ---- convert W_hh into MFMA-B fragment layout
__global__ void wfrag_kernel(const float* __restrict__ W, short* __restrict__ Wf) {
  const int bid = blockIdx.x;  // nt*32 + kt
  const int nn = threadIdx.x & 15, kk = threadIdx.x >> 4;
  const int l = (kk >> 2) * 16 + nn;
  const int jj = (kk & 3) * 2;
  const int nt = bid >> 5, kt = bid & 31;
  const int n = nt * 16 + nn;
  const int k = kt * 32 + (kk >> 2) * 8 + jj;
  unsigned lo = (unsigned)(unsigned short)f2bf(W[(size_t)k * Kd + n]);
  unsigned hi = (unsigned)(unsigned short)f2bf(W[(size_t)(k + 1) * Kd + n]);
  ((unsigned*)Wf)[((size_t)bid * 64 + l) * 4 + (jj >> 1)] = lo | (hi << 16);
}

// ---- convert inp f32 -> bf16
__global__ void icvt_kernel(const float* __restrict__ inp, short* __restrict__ out) {
  int i = blockIdx.x * 2048 + threadIdx.x * 8;
  float4 a = *(const float4*)(inp + i);
  float4 b = *(const float4*)(inp + i + 4);
  s16x8 v;
  v[0] = f2bf(a.x); v[1] = f2bf(a.y); v[2] = f2bf(a.z); v[3] = f2bf(a.w);
  v[4] = f2bf(b.x); v[5] = f2bf(b.y); v[6] = f2bf(b.z); v[7] = f2bf(b.w);
  *(s16x8*)(out + i) = v;
}

// ---- P_raw = inp_bf16 @ W_ih
__global__ void __launch_bounds__(256) gemm_p_kernel(const short* __restrict__ A,
                                                     const short* __restrict__ BT,
                                                     short* __restrict__ C) {
  const int n0 = blockIdx.x * 64, m0 = blockIdx.y * 64;
  const int tid = threadIdx.x, w = tid >> 6, l = tid & 63, lm = l & 15, q = l >> 4;
  const short* ap = A + (m0 + w * 16 + lm) * Kd + q * 8;
  const short* bp = BT + (n0 + lm) * Kd + q * 8;
  f32x4 acc0 = {0.f, 0.f, 0.f, 0.f}, acc1 = acc0, acc2 = acc0, acc3 = acc0;
#pragma unroll 4
  for (int k = 0; k < Kd; k += 32) {
    s16x8 a = *(const s16x8*)(ap + k);
    s16x8 b0 = *(const s16x8*)(bp + k);
    s16x8 b1 = *(const s16x8*)(bp + 16 * Kd + k);
    s16x8 b2 = *(const s16x8*)(bp + 32 * Kd + k);
    s16x8 b3 = *(const s16x8*)(bp + 48 * Kd + k);
    acc0 = __builtin_amdgcn_mfma_f32_16x16x32_bf16(a, b0, acc0, 0, 0, 0);
    acc1 = __builtin_amdgcn_mfma_f32_16x16x32_bf16(a, b1, acc1, 0, 0, 0);
    acc2 = __builtin_amdgcn_mfma_f32_16x16x32_bf16(a, b2, acc2, 0, 0, 0);
    acc3 = __builtin_amdgcn_mfma_f32_16x16x32_bf16(a, b3, acc3, 0, 0, 0);
  }
  const int row = m0 + w * 16 + q * 4, col = n0 + lm;
#pragma unroll
  for (int r = 0; r < 4; r++) {
    C[(row + r) * Kd + col] = f2bf(acc0[r]);
    C[(row + r) * Kd + col + 16] = f2bf(acc1[r]);
    C[(row + r) * Kd + col + 32] = f2bf(acc2[r]);
    C[(row + r) * Kd + col + 48] = f2bf(acc3[r]);
  }
}

// ---- per-row mobius_matvec scaling of P; store pn2 = ||p||^2, pb2 = p.b
__global__ void __launch_bounds__(256) rowscale_kernel(const float* __restrict__ inp,
                                                       const float* __restrict__ bh,
                                                       short* __restrict__ P,
                                                       float* __restrict__ pn2,
                                                       float* __restrict__ pb2) {
  const int r = blockIdx.x, tid = threadIdx.x, i0 = tid * 4;
  float4 xv = *(const float4*)(inp + r * Kd + i0);
  float xn2 = brsum(xv.x * xv.x + xv.y * xv.y + xv.z * xv.z + xv.w * xv.w);
  s16x4 pr = *(const s16x4*)(P + r * Kd + i0);
  float p0 = bf2f(pr[0]), p1 = bf2f(pr[1]), p2 = bf2f(pr[2]), p3 = bf2f(pr[3]);
  float mxn2 = brsum(p0 * p0 + p1 * p1 + p2 * p2 + p3 * p3);
  float xn = fmaxf(sqrtf(xn2), EPSF);
  float mxn = fmaxf(sqrtf(mxn2), EPSF);
  float sc = tanhf(mxn / xn * atanhf(fminf(xn, ONEM))) / mxn;
  s16x4 po;
  po[0] = f2bf(sc * p0); po[1] = f2bf(sc * p1);
  po[2] = f2bf(sc * p2); po[3] = f2bf(sc * p3);
  *(s16x4*)(P + r * Kd + i0) = po;
  float4 bv = *(const float4*)(bh + i0);
  float s0 = bf2f(po[0]), s1 = bf2f(po[1]), s2v = bf2f(po[2]), s3 = bf2f(po[3]);
  float pn2v = brsum(s0 * s0 + s1 * s1 + s2v * s2v + s3 * s3);
  float pbv = brsum(s0 * bv.x + s1 * bv.y + s2v * bv.z + s3 * bv.w);
  if (tid == 0) { pn2[r] = pn2v; pb2[r] = pbv; }
}

// ---- phase 2: 256 blocks = 16 groups x 16 N-blocks; W_hh slice PINNED in
// registers (inline-asm keep-alive); u exchanged via LLC (relaxed atomics),
// staged cooperatively into LDS once per block per step.
__global__ void __launch_bounds__(256, 1) rnn_kernel(
    const short* __restrict__ Wf, const short* __restrict__ P,
    const float* __restrict__ pn2, const float* __restrict__ pb2,
    const float* __restrict__ bh, float* __restrict__ out,
    float* __restrict__ S, int* __restrict__ cnt, ull* __restrict__ ubuf) {
  __shared__ short us[16][1032];  // staged u rows (stride 2064B: 2-way = free)
  __shared__ float red[4][16][4];
  __shared__ float bex[4];
  const int tid = threadIdx.x, w = tid >> 6, l = tid & 63, lm = l & 15, q = l >> 4;
  const int g = blockIdx.x & 15, nb = blockIdx.x >> 4;
  const int gr0 = g * 16;
  const int c = nb * 64 + w * 16 + lm;  // my output column
  const int nt = nb * 4 + w;            // Wf 16-col tile index

  // zero us (h0 = 0 for the t=0 GEMM)
  for (int i = tid; i < 8256; i += 256) ((int*)us)[i] = 0;

  // ---- b2 = ||b||^2 (block-wide) and my bias value
  float4 bv4 = *(const float4*)(bh + tid * 4);
  float bp = bv4.x * bv4.x + bv4.y * bv4.y + bv4.z * bv4.z + bv4.w * bv4.w;
#pragma unroll
  for (int m = 32; m >= 1; m >>= 1) bp += __shfl_xor(bp, m, 64);
  if (l == 0) bex[w] = bp;
  __syncthreads();  // covers us zero + bex
  const float b2 = bex[0] + bex[1] + bex[2] + bex[3];
  const float bb = bh[c];

  // ---- W_hh B-fragments for my 16-col strip: 32 x 16B = 128 VGPRs
  s16x8 wfr[32];
#pragma unroll
  for (int kt = 0; kt < 32; kt++)
    wfr[kt] = *(const s16x8*)(Wf + ((size_t)(nt * 32 + kt) * 64 + l) * 8);

  const short* ar = &us[0][0] + lm * 1032 + q * 8;  // A-frag base in LDS
  float lam[4] = {1.f, 1.f, 1.f, 1.f};
  float hn2c[4] = {0.f, 0.f, 0.f, 0.f};

  for (int t = 0; t < Tt; t++) {
    // PIN wfr: asm claims to modify each fragment -> compiler cannot
    // rematerialize the Wf loads; 128 VGPRs stay live across the loop.
#pragma unroll
    for (int kt = 0; kt < 32; kt++) asm volatile("" : "+v"(wfr[kt]));

    // prefetch p and per-row precomputed dots (plain loads: read-only inputs)
    float pv[4], p2s[4], pbr[4];
#pragma unroll
    for (int r = 0; r < 4; r++) {
      size_t rt = (size_t)(gr0 + q * 4 + r) * Tt + t;
      pv[r] = bf2f(P[rt * Kd + c]);
      p2s[r] = pn2[rt];
      pbr[r] = pb2[rt];
    }

    // ---- GEMM: u(t-1) @ W_hh (A-frags from LDS, B-frags pinned registers)
    f32x4 c0 = {0.f, 0.f, 0.f, 0.f}, c1v = c0, c2v = c0, c3v = c0;
#pragma unroll
    for (int kt = 0; kt < 32; kt += 4) {
      s16x8 a0 = *(const s16x8*)(ar + (kt + 0) * 32);
      s16x8 a1 = *(const s16x8*)(ar + (kt + 1) * 32);
      s16x8 a2 = *(const s16x8*)(ar + (kt + 2) * 32);
      s16x8 a3 = *(const s16x8*)(ar + (kt + 3) * 32);
      c0 = __builtin_amdgcn_mfma_f32_16x16x32_bf16(a0, wfr[kt], c0, 0, 0, 0);
      c1v = __builtin_amdgcn_mfma_f32_16x16x32_bf16(a1, wfr[kt + 1], c1v, 0, 0, 0);
      c2v = __builtin_amdgcn_mfma_f32_16x16x32_bf16(a2, wfr[kt + 2], c2v, 0, 0, 0);
      c3v = __builtin_amdgcn_mfma_f32_16x16x32_bf16(a3, wfr[kt + 3], c3v, 0, 0, 0);
    }
    f32x4 accv = (c0 + c1v) + (c2v + c3v);
    float mx[4];
#pragma unroll
    for (int r = 0; r < 4; r++) mx[r] = lam[r] * accv[r];

    // ---- R1 partials: {mx^2, mx*b, p*mx} over my 16 cols
#pragma unroll
    for (int r = 0; r < 4; r++) {
      float vm2 = red16(mx[r] * mx[r]);
      float vmb = red16(mx[r] * bb);
      float vpm = red16(pv[r] * mx[r]);
      if (lm == 0) {
        red[w][q * 4 + r][0] = vm2;
        red[w][q * 4 + r][1] = vmb;
        red[w][q * 4 + r][2] = vpm;
      }
    }
    __syncthreads();
    float* Sg = S + ((size_t)t * 16 + g) * 64;  // [16 rows][4]
    if (tid < 64) {
      int row = tid >> 2, s = tid & 3;
      if (s < 3) {
        float v = red[0][row][s] + red[1][row][s] + red[2][row][s] + red[3][row][s];
        __hip_atomic_fetch_add(&Sg[row * 4 + s], v, __ATOMIC_RELAXED,
                               __HIP_MEMORY_SCOPE_AGENT);
      }
    }
    int* cg = cnt + ((size_t)t * 16 + g) * 16;  // 64B line per (t,g)
    gbarR(cg);

    // ---- read dots (ATOMIC: bypass stale L1/L2), scalar mobius algebra
    float uu[4], u2p[4];
#pragma unroll
    for (int r = 0; r < 4; r++) {
      PF d01;
      d01.u = __hip_atomic_load((ull*)Sg + (q * 4 + r) * 2, __ATOMIC_RELAXED,
                                __HIP_MEMORY_SCOPE_AGENT);
      float Spm = __hip_atomic_load(&Sg[(q * 4 + r) * 4 + 2], __ATOMIC_RELAXED,
                                    __HIP_MEMORY_SCOPE_AGENT);
      float Smm = d01.f[0], Smb = d01.f[1];
      float hn = fmaxf(sqrtf(hn2c[r]), EPSF);
      float mxn = fmaxf(sqrtf(Smm), EPSF);
      float sc = ftanh(mxn / hn * fatanh(fminf(hn, ONEM))) / mxn;
      float x2 = sc * sc * Smm;
      float xy = sc * Smb;
      float den = fmaxf(1.f + 2.f * xy + x2 * b2, EPSF);
      float al = ((1.f + 2.f * xy + b2) / den) * sc;  // hv = al*mx + be*b
      float be = (1.f - x2) / den;
      float hh2 = al * al * Smm + 2.f * al * be * Smb + be * be * b2;
      float ph = al * Spm + be * pbr[r];
      float den2 = fmaxf(1.f + 2.f * ph + p2s[r] * hh2, EPSF);
      float cc1 = (1.f + 2.f * ph + hh2) / den2;
      float cc2 = (1.f - p2s[r]) / den2;
      float z = cc1 * pv[r] + cc2 * (al * mx[r] + be * bb);
      float z2 = cc1 * cc1 * p2s[r] + cc2 * cc2 * hh2 + 2.f * cc1 * cc2 * ph;
      float zn = fmaxf(sqrtf(z2), EPSF);
      float gg = fatanh(fminf(zn, ONEM)) / zn;
      uu[r] = ftanh(gg * z);
      u2p[r] = red16(uu[r] * uu[r]);
    }

    // ---- R2: u exchange (packed 4xbf16 per 8B relaxed atomic) + u^2 sums
    const int p = t & 1;
    ull* ubw = ubuf + ((size_t)(p * 16 + g) * 16) * 256;  // [16 rows][256]
    const int ent = nb * 16 + w * 4 + (lm >> 2);
#pragma unroll
    for (int r = 0; r < 4; r++) {
      unsigned v16 = (unsigned)(unsigned short)f2bf(uu[r]);
      unsigned o1 = (unsigned)__shfl_xor((int)v16, 1, 64);
      unsigned plo = v16 | (o1 << 16);                       // even lm
      unsigned phi = (unsigned)__shfl_xor((int)plo, 2, 64);  // from lm+2
      if ((lm & 3) == 0) {
        ull pk = (ull)plo | ((ull)phi << 32);
        __hip_atomic_store(&ubw[(q * 4 + r) * 256 + ent], pk, __ATOMIC_RELAXED,
                           __HIP_MEMORY_SCOPE_AGENT);
      }
      if (lm == 0) red[w][q * 4 + r][3] = u2p[r];
    }
    __syncthreads();
    if (tid < 16) {
      float v = red[0][tid][3] + red[1][tid][3] + red[2][tid][3] + red[3][tid][3];
      __hip_atomic_fetch_add(&Sg[tid * 4 + 3], v, __ATOMIC_RELAXED,
                             __HIP_MEMORY_SCOPE_AGENT);
    }
    gbarR(cg + 8);

#pragma unroll
    for (int r = 0; r < 4; r++) {
      float u2 = __hip_atomic_load(&Sg[(q * 4 + r) * 4 + 3], __ATOMIC_RELAXED,
                                   __HIP_MEMORY_SCOPE_AGENT);
      float un = fmaxf(sqrtf(u2), EPSF);
      float s2 = ftanh(un) / un;
      lam[r] = s2;
      hn2c[r] = s2 * s2 * u2;
      if (t == Tt - 1)
        out[(size_t)(gr0 + q * 4 + r) * Kd + c] = s2 * uu[r];
    }

    // ---- cooperative stage of u(t) from LLC into LDS for next step's GEMM
    const ull* ub = ubuf + ((size_t)(p * 16 + g) * 16) * 256;
#pragma unroll
    for (int i = 0; i < 16; i++) {
      ull v = __hip_atomic_load(&ub[i * 256 + tid], __ATOMIC_RELAXED,
                                __HIP_MEMORY_SCOPE_AGENT);
      *(ull*)&us[i][tid * 4] = v;
    }
    __syncthreads();  // us ready before next GEMM
  }
}

extern "C" void kernel_launch(void* const* d_in, const int* in_sizes, int n_in,
                              void* d_out, int out_size, void* d_ws, size_t ws_size,
                              hipStream_t stream) {
  const float* inp = (const float*)d_in[0];  // [256][128][1024]
  const float* Wih = (const float*)d_in[1];  // [1024][1024]
  const float* Whh = (const float*)d_in[2];  // [1024][1024]
  const float* bh = (const float*)d_in[3];   // [1024]

  char* ws = (char*)d_ws;
  size_t off = 0;
  float* S = (float*)(ws + off); off += (size_t)Tt * 16 * 64 * 4;        // 512KB
  int* cnt = (int*)(ws + off); off += (size_t)Tt * 16 * 16 * 4;          // 128KB
  size_t zbytes = off;
  ull* ubuf = (ull*)(ws + off); off += (size_t)2 * 16 * 16 * 256 * 8;    // 1MB
  float* pn2 = (float*)(ws + off); off += (size_t)Bb * Tt * 4;           // 128KB
  float* pb2 = (float*)(ws + off); off += (size_t)Bb * Tt * 4;           // 128KB
  short* WTih = (short*)(ws + off); off += (size_t)Kd * Kd * 2;          // 2MB
  short* Wfhh = (short*)(ws + off); off += (size_t)Kd * Kd * 2;          // 2MB
  short* Ab = (short*)(ws + off); off += (size_t)Bb * Tt * Kd * 2;       // 64MB
  short* P = (short*)(ws + off); off += (size_t)Bb * Tt * Kd * 2;        // 64MB

  hipMemsetAsync(d_ws, 0, zbytes, stream);  // S sums + counters

  wcvt_kernel<<<dim3(16, 16), 256, 0, stream>>>(Wih, WTih);
  wfrag_kernel<<<2048, 256, 0, stream>>>(Whh, Wfhh);
  icvt_kernel<<<(Bb * Tt * Kd) / 2048, 256, 0, stream>>>(inp, Ab);
  gemm_p_kernel<<<dim3(16, (Bb * Tt) / 64), 256, 0, stream>>>(Ab, WTih, P);
  rowscale_kernel<<<Bb * Tt, 256, 0, stream>>>(inp, bh, P, pn2, pb2);
  rnn_kernel<<<256, 256, 0, stream>>>(Wfhh, P, pn2, pb2, bh, (float*)d_out,
                                      S, cnt, ubuf);
}